// Round 6
// baseline (231.256 us; speedup 1.0000x reference)
//
#include <hip/hip_runtime.h>
#include <hip/hip_bf16.h>
#include <math.h>

#define NN 50000
#define EE 800000
#define FIN 256
#define FH 96
#define FC 40
#define NBK 196   // ceil(50000/256) buckets of 256 nodes

// ---------------- privatized LDS histogram (deg by row, cnt by col) ----------------

__global__ __launch_bounds__(256) void k_hist(const int* __restrict__ ei, int E,
                                              unsigned* __restrict__ copies) {
    __shared__ unsigned hist[12500];
    int b = blockIdx.x;
    int slice = b & 63;
    int half = (b >> 6) & 1;
    int arr = b >> 7;
    const int* ptr = ei + (size_t)arr * E;  // arr=0: row, arr=1: col
    int tid = threadIdx.x;
    for (int i = tid; i < 12500; i += 256) hist[i] = 0u;
    __syncthreads();
    int ES = (E + 63) >> 6;
    int lo = slice * ES, hi = min(lo + ES, E);
    int nlo = half * 25000;
    for (int i = lo + tid; i < hi; i += 256) {
        int rel = ptr[i] - nlo;
        if ((unsigned)rel < 25000u)
            atomicAdd(&hist[rel >> 1], 1u << ((rel & 1) << 4));
    }
    __syncthreads();
    unsigned* dst = copies + (size_t)((arr * 2 + half) * 64 + slice) * 12500;
    for (int i = tid; i < 12500; i += 256) dst[i] = hist[i];
}

// sum the 64 copies -> dinv (float, rsqrt(deg+1)) and cnt (u32)
__global__ void k_reduce(const unsigned* __restrict__ copies,
                         float* __restrict__ dinv, unsigned* __restrict__ cnt) {
    int t = blockIdx.x * blockDim.x + threadIdx.x;  // 0..24999
    if (t >= 25000) return;
    int half = t / 12500, w = t - half * 12500;
    unsigned sr = 0, sc = 0;
    const unsigned* br = copies + (size_t)(half) * 64 * 12500 + w;      // rows
    const unsigned* bc = copies + (size_t)(2 + half) * 64 * 12500 + w;  // cols
#pragma unroll 8
    for (int s = 0; s < 64; ++s) { sr += br[s * 12500]; sc += bc[s * 12500]; }
    int n0 = half * 25000 + 2 * w;
    dinv[n0]     = rsqrtf((float)((sr & 0xffffu) + 1u));
    dinv[n0 + 1] = rsqrtf((float)((sr >> 16) + 1u));
    cnt[n0]     = sc & 0xffffu;
    cnt[n0 + 1] = sc >> 16;
}

// ---------------- exclusive scan of cnt -> off ----------------

__global__ __launch_bounds__(1024) void k_scanA(const unsigned* __restrict__ cnt,
                                                unsigned* __restrict__ off,
                                                unsigned* __restrict__ bsum, int n) {
    __shared__ unsigned s[1024];
    int t = threadIdx.x;
    int i = blockIdx.x * 1024 + t;
    unsigned v = (i < n) ? cnt[i] : 0u;
    s[t] = v;
    __syncthreads();
    for (int o = 1; o < 1024; o <<= 1) {
        unsigned tv = (t >= o) ? s[t - o] : 0u;
        __syncthreads();
        s[t] += tv;
        __syncthreads();
    }
    if (i < n) off[i] = s[t] - v;  // exclusive
    if (t == 1023) bsum[blockIdx.x] = s[1023];
}

__global__ void k_scanB1(unsigned* bsum, int nb) {
    if (threadIdx.x == 0 && blockIdx.x == 0) {
        unsigned run = 0;
        for (int b = 0; b < nb; ++b) { unsigned tv = bsum[b]; bsum[b] = run; run += tv; }
    }
}

__global__ void k_scanB2(unsigned* __restrict__ off, const unsigned* __restrict__ bsum,
                         int n, unsigned e) {
    int i = blockIdx.x * blockDim.x + threadIdx.x;
    if (i < n) off[i] = off[i] + bsum[i >> 10];
    if (i == n) off[n] = e;
}

// gcur[b] = off[b*256]
__global__ void k_initgc(const unsigned* __restrict__ off, unsigned* __restrict__ gcur) {
    int b = threadIdx.x + blockIdx.x * blockDim.x;
    if (b < NBK) gcur[b] = off[b * 256];
}

// ---------------- P1: coarse bucket by col>>8 (count, reserve, place) ----------------

__global__ __launch_bounds__(256) void k_bucket(const int* __restrict__ row,
                                                const int* __restrict__ col,
                                                const float* __restrict__ ew,
                                                unsigned* __restrict__ gcur,
                                                unsigned* __restrict__ bkc,
                                                float2* __restrict__ bkrw, int E) {
    __shared__ unsigned cnt[NBK];
    __shared__ unsigned cur[NBK];
    int tid = threadIdx.x;
    int CH = (E + gridDim.x - 1) / gridDim.x;
    int lo = blockIdx.x * CH, hi = min(lo + CH, E);
    for (int i = tid; i < NBK; i += 256) cnt[i] = 0u;
    __syncthreads();
    for (int i = lo + tid; i < hi; i += 256) atomicAdd(&cnt[col[i] >> 8], 1u);
    __syncthreads();
    for (int i = tid; i < NBK; i += 256) cur[i] = atomicAdd(&gcur[i], cnt[i]);
    __syncthreads();
    for (int i = lo + tid; i < hi; i += 256) {
        int c = col[i];
        unsigned pos = atomicAdd(&cur[c >> 8], 1u);
        bkc[pos] = (unsigned)c;
        float2 p;
        p.x = __int_as_float(row[i]);
        p.y = ew[i];
        bkrw[pos] = p;
    }
}

// ---------------- P2: exact place within bucket (block = bucket, contiguous epk slice) ----------------

__global__ __launch_bounds__(256) void k_place(const unsigned* __restrict__ bkc,
                                               const float2* __restrict__ bkrw,
                                               const unsigned* __restrict__ off,
                                               float2* __restrict__ epk, int n) {
    __shared__ unsigned cur[256];
    int b = blockIdx.x;
    int tid = threadIdx.x;
    int node0 = b * 256;
    int node = node0 + tid;
    cur[tid] = off[(node <= n) ? node : n];
    __syncthreads();
    unsigned st = off[node0];
    unsigned en = off[min(node0 + 256, n)];
    for (unsigned i = st + tid; i < en; i += 256) {
        unsigned c = bkc[i];
        unsigned pos = atomicAdd(&cur[c & 255], 1u);
        epk[pos] = bkrw[i];
    }
}

// ---------------- GEMM1 (split-K x2): partial = x @ W1^T over K half ----------------

__global__ __launch_bounds__(256) void k_gemm1(const float* __restrict__ x,
                                               const float* __restrict__ W,
                                               float* __restrict__ g0a,
                                               float* __restrict__ g0b, int n) {
    __shared__ float xs[32][132];
    __shared__ float ws[32][100];
    int tid = threadIdx.x;
    int row0 = blockIdx.x * 128;
    int rg = tid & 31, cg = tid >> 5;
    float* dst = blockIdx.y ? g0b : g0a;
    int kbase = blockIdx.y * 128;

    float acc[4][12];
#pragma unroll
    for (int r = 0; r < 4; ++r)
#pragma unroll
        for (int c = 0; c < 12; ++c) acc[r][c] = 0.f;

    for (int k0 = kbase; k0 < kbase + 128; k0 += 32) {
#pragma unroll
        for (int i = 0; i < 4; ++i) {
            int f4i = tid + 256 * i;
            int gr = f4i >> 3;
            int kk = (f4i & 7) << 2;
            int grow = row0 + gr;
            float4 v = make_float4(0.f, 0.f, 0.f, 0.f);
            if (grow < n) v = *(const float4*)&x[grow * FIN + k0 + kk];
            xs[kk + 0][gr] = v.x; xs[kk + 1][gr] = v.y;
            xs[kk + 2][gr] = v.z; xs[kk + 3][gr] = v.w;
        }
#pragma unroll
        for (int i = 0; i < 3; ++i) {
            int f4i = tid + 256 * i;
            int wc = f4i >> 3;
            int kk = (f4i & 7) << 2;
            float4 v = *(const float4*)&W[wc * FIN + k0 + kk];
            ws[kk + 0][wc] = v.x; ws[kk + 1][wc] = v.y;
            ws[kk + 2][wc] = v.z; ws[kk + 3][wc] = v.w;
        }
        __syncthreads();
#pragma unroll 8
        for (int k = 0; k < 32; ++k) {
            float4 xv = *(const float4*)&xs[k][4 * rg];
            float4 w0 = *(const float4*)&ws[k][4 * cg];
            float4 w1 = *(const float4*)&ws[k][4 * cg + 32];
            float4 w2 = *(const float4*)&ws[k][4 * cg + 64];
            const float xr[4] = {xv.x, xv.y, xv.z, xv.w};
#pragma unroll
            for (int r = 0; r < 4; ++r) {
                acc[r][0]  = fmaf(xr[r], w0.x, acc[r][0]);
                acc[r][1]  = fmaf(xr[r], w0.y, acc[r][1]);
                acc[r][2]  = fmaf(xr[r], w0.z, acc[r][2]);
                acc[r][3]  = fmaf(xr[r], w0.w, acc[r][3]);
                acc[r][4]  = fmaf(xr[r], w1.x, acc[r][4]);
                acc[r][5]  = fmaf(xr[r], w1.y, acc[r][5]);
                acc[r][6]  = fmaf(xr[r], w1.z, acc[r][6]);
                acc[r][7]  = fmaf(xr[r], w1.w, acc[r][7]);
                acc[r][8]  = fmaf(xr[r], w2.x, acc[r][8]);
                acc[r][9]  = fmaf(xr[r], w2.y, acc[r][9]);
                acc[r][10] = fmaf(xr[r], w2.z, acc[r][10]);
                acc[r][11] = fmaf(xr[r], w2.w, acc[r][11]);
            }
        }
        __syncthreads();
    }
#pragma unroll
    for (int r = 0; r < 4; ++r) {
        int grow = row0 + 4 * rg + r;
        if (grow < n) {
#pragma unroll
            for (int c = 0; c < 3; ++c) {
                float4 v = make_float4(acc[r][4 * c], acc[r][4 * c + 1],
                                       acc[r][4 * c + 2], acc[r][4 * c + 3]);
                *(float4*)&dst[grow * FH + 4 * cg + 32 * c] = v;
            }
        }
    }
}

// ---------------- combine split-K partials: g0a = dinv ⊙ (g0a + g0b) ----------------

__global__ void k_comb(float* __restrict__ g0a, const float* __restrict__ g0b,
                       const float* __restrict__ dinv, int n) {
    int j = blockIdx.x * blockDim.x + threadIdx.x;  // over n*24 float4s
    if (j >= n * 24) return;
    int node = j / 24;
    float s = dinv[node];
    float4 a = ((float4*)g0a)[j];
    float4 b = ((const float4*)g0b)[j];
    a.x = s * (a.x + b.x);
    a.y = s * (a.y + b.y);
    a.z = s * (a.z + b.z);
    a.w = s * (a.w + b.w);
    ((float4*)g0a)[j] = a;
}

// ---------------- aggregation 96: h = relu(dinv[c]*(g0[c] + Σ ew*g0[r]) + b1) ----------------

__global__ __launch_bounds__(256) void k_agg96(const float* __restrict__ g0,
                                               const unsigned* __restrict__ off,
                                               const float2* __restrict__ epk,
                                               const float* __restrict__ dinv,
                                               const float* __restrict__ b,
                                               float* __restrict__ outh, int n) {
    int tid = blockIdx.x * 256 + threadIdx.x;
    int node = tid / 24;
    int f4 = tid - node * 24;
    if (node >= n) return;
    float4 acc = ((const float4*)g0)[node * 24 + f4];
    unsigned st = off[node], en = off[node + 1];
    for (unsigned e = st; e < en; ++e) {
        float2 p = epk[e];
        int r = __float_as_int(p.x);
        float wv = p.y;
        float4 v = ((const float4*)g0)[r * 24 + f4];
        acc.x = fmaf(wv, v.x, acc.x);
        acc.y = fmaf(wv, v.y, acc.y);
        acc.z = fmaf(wv, v.z, acc.z);
        acc.w = fmaf(wv, v.w, acc.w);
    }
    float s = dinv[node];
    float4 bv = ((const float4*)b)[f4];
    acc.x = fmaxf(fmaf(s, acc.x, bv.x), 0.f);
    acc.y = fmaxf(fmaf(s, acc.y, bv.y), 0.f);
    acc.z = fmaxf(fmaf(s, acc.z, bv.z), 0.f);
    acc.w = fmaxf(fmaf(s, acc.w, bv.w), 0.f);
    ((float4*)outh)[node * 24 + f4] = acc;
}

// ---------------- GEMM2: g1 = dinv ⊙ (h @ W2^T) ----------------

__global__ __launch_bounds__(256) void k_gemm2(const float* __restrict__ h,
                                               const float* __restrict__ W,
                                               const float* __restrict__ dinv,
                                               float* __restrict__ g1, int n) {
    __shared__ float hs[48][132];
    __shared__ float w2s[48][44];
    int tid = threadIdx.x;
    int row0 = blockIdx.x * 128;
    int rg = tid & 31, cg = tid >> 5;

    float acc[4][5];
#pragma unroll
    for (int r = 0; r < 4; ++r)
#pragma unroll
        for (int c = 0; c < 5; ++c) acc[r][c] = 0.f;

    for (int k0 = 0; k0 < FH; k0 += 48) {
#pragma unroll
        for (int i = 0; i < 6; ++i) {
            int f4i = tid + 256 * i;
            int gr = f4i / 12;
            int kk = (f4i - gr * 12) << 2;
            int grow = row0 + gr;
            float4 v = make_float4(0.f, 0.f, 0.f, 0.f);
            if (grow < n) v = *(const float4*)&h[grow * FH + k0 + kk];
            hs[kk + 0][gr] = v.x; hs[kk + 1][gr] = v.y;
            hs[kk + 2][gr] = v.z; hs[kk + 3][gr] = v.w;
        }
#pragma unroll
        for (int i = 0; i < 2; ++i) {
            int f4i = tid + 256 * i;
            if (f4i < 480) {
                int wc = f4i / 12;
                int kk = (f4i - wc * 12) << 2;
                float4 v = *(const float4*)&W[wc * FH + k0 + kk];
                w2s[kk + 0][wc] = v.x; w2s[kk + 1][wc] = v.y;
                w2s[kk + 2][wc] = v.z; w2s[kk + 3][wc] = v.w;
            }
        }
        __syncthreads();
#pragma unroll 8
        for (int k = 0; k < 48; ++k) {
            float4 xv = *(const float4*)&hs[k][4 * rg];
            const float xr[4] = {xv.x, xv.y, xv.z, xv.w};
            float wv[5];
#pragma unroll
            for (int c = 0; c < 5; ++c) wv[c] = w2s[k][5 * cg + c];
#pragma unroll
            for (int r = 0; r < 4; ++r)
#pragma unroll
                for (int c = 0; c < 5; ++c)
                    acc[r][c] = fmaf(xr[r], wv[c], acc[r][c]);
        }
        __syncthreads();
    }
#pragma unroll
    for (int r = 0; r < 4; ++r) {
        int grow = row0 + 4 * rg + r;
        if (grow < n) {
            float dv = dinv[grow];
#pragma unroll
            for (int c = 0; c < 5; ++c) g1[grow * FC + 5 * cg + c] = dv * acc[r][c];
        }
    }
}

// ---------------- aggregation 40: out = dinv[c]*(g1[c] + Σ ew*g1[r]) + b2 ----------------

__global__ __launch_bounds__(256) void k_agg40(const float* __restrict__ g1,
                                               const unsigned* __restrict__ off,
                                               const float2* __restrict__ epk,
                                               const float* __restrict__ dinv,
                                               const float* __restrict__ b,
                                               float* __restrict__ out, int n) {
    int tid = blockIdx.x * 256 + threadIdx.x;
    int node = tid / 10;
    int f4 = tid - node * 10;
    if (node >= n) return;
    float4 acc = ((const float4*)g1)[node * 10 + f4];
    unsigned st = off[node], en = off[node + 1];
    for (unsigned e = st; e < en; ++e) {
        float2 p = epk[e];
        int r = __float_as_int(p.x);
        float wv = p.y;
        float4 v = ((const float4*)g1)[r * 10 + f4];
        acc.x = fmaf(wv, v.x, acc.x);
        acc.y = fmaf(wv, v.y, acc.y);
        acc.z = fmaf(wv, v.z, acc.z);
        acc.w = fmaf(wv, v.w, acc.w);
    }
    float s = dinv[node];
    float4 bv = ((const float4*)b)[f4];
    acc.x = fmaf(s, acc.x, bv.x);
    acc.y = fmaf(s, acc.y, bv.y);
    acc.z = fmaf(s, acc.z, bv.z);
    acc.w = fmaf(s, acc.w, bv.w);
    ((float4*)out)[node * 10 + f4] = acc;
}

// ---------------- log_softmax (wave per row) ----------------

__global__ void k_lsm(float* __restrict__ out, int n) {
    int gtid = blockIdx.x * blockDim.x + threadIdx.x;
    int wid = gtid >> 6;
    int lane = threadIdx.x & 63;
    if (wid >= n) return;
    float vv = 0.f, v = -INFINITY;
    if (lane < FC) {
        vv = out[wid * FC + lane];
        v = vv;
    }
#pragma unroll
    for (int o = 32; o; o >>= 1) v = fmaxf(v, __shfl_xor(v, o));
    float ex = (lane < FC) ? expf(vv - v) : 0.f;
#pragma unroll
    for (int o = 32; o; o >>= 1) ex += __shfl_xor(ex, o);
    float lse = logf(ex) + v;
    if (lane < FC) out[wid * FC + lane] = vv - lse;
}

// ---------------- launch ----------------

extern "C" void kernel_launch(void* const* d_in, const int* in_sizes, int n_in,
                              void* d_out, int out_size, void* d_ws, size_t ws_size,
                              hipStream_t stream) {
    const float* x  = (const float*)d_in[0];
    const int*   ei = (const int*)d_in[1];
    const float* ew = (const float*)d_in[2];
    const float* W1 = (const float*)d_in[3];
    const float* b1 = (const float*)d_in[4];
    const float* W2 = (const float*)d_in[5];
    const float* b2 = (const float*)d_in[6];
    float* out = (float*)d_out;

    const int N = NN;
    const int E = in_sizes[1] / 2;
    const int* row = ei;
    const int* col = ei + E;

    float* ws = (float*)d_ws;
    // workspace layout (4-byte words); total 11,350,976 words = 45.4 MB
    // temporal overlays of region R = [150976, 4950976):
    //   copies [150976,3350976)            : k_hist -> k_reduce
    //   bkc [150976,950976), bkrw [950976,2550976) : k_bucket -> k_place
    //   g0b [150976,4950976)               : k_gemm1 -> k_comb
    //   h   [150976,4950976)               : k_agg96 -> k_gemm2
    // epk [4950976,6550976): k_place -> k_agg40
    // g0a [6550976,11350976): k_gemm1 -> k_agg96; then g1 (gemm2 -> agg40)
    float*    dinv   = (float*)(ws + 0);           // N
    unsigned* cnt    = (unsigned*)(ws + 50176);    // N
    unsigned* off    = (unsigned*)(ws + 100352);   // N+1
    unsigned* bsum   = (unsigned*)(ws + 150656);   // 64
    unsigned* gcur   = (unsigned*)(ws + 150720);   // 196 (+pad to 150976)
    unsigned* copies = (unsigned*)(ws + 150976);   // 4*64*12500
    unsigned* bkc    = (unsigned*)(ws + 150976);   // E
    float2*   bkrw   = (float2*)(ws + 950976);     // E float2
    float*    g0b    = ws + 150976;                // N*96
    float*    h      = ws + 150976;                // N*96
    float2*   epk    = (float2*)(ws + 4950976);    // E float2
    float*    g0a    = ws + 6550976;               // N*96 (reused as g1)
    float*    g1     = g0a;

    const int B = 256;
    const int NB_SCAN = (N + 1023) / 1024;

    hipLaunchKernelGGL(k_hist, dim3(256), dim3(B), 0, stream, ei, E, copies);
    hipLaunchKernelGGL(k_reduce, dim3((25000 + B - 1) / B), dim3(B), 0, stream, copies, dinv, cnt);

    hipLaunchKernelGGL(k_scanA, dim3(NB_SCAN), dim3(1024), 0, stream, cnt, off, bsum, N);
    hipLaunchKernelGGL(k_scanB1, dim3(1), dim3(64), 0, stream, bsum, NB_SCAN);
    hipLaunchKernelGGL(k_scanB2, dim3((N + 1 + B - 1) / B), dim3(B), 0, stream, off, bsum, N, (unsigned)E);
    hipLaunchKernelGGL(k_initgc, dim3(1), dim3(B), 0, stream, off, gcur);

    hipLaunchKernelGGL(k_bucket, dim3(320), dim3(B), 0, stream, row, col, ew, gcur, bkc, bkrw, E);
    hipLaunchKernelGGL(k_place, dim3(NBK), dim3(B), 0, stream, bkc, bkrw, off, epk, N);

    hipLaunchKernelGGL(k_gemm1, dim3((N + 127) / 128, 2), dim3(B), 0, stream, x, W1, g0a, g0b, N);
    hipLaunchKernelGGL(k_comb, dim3((N * 24 + B - 1) / B), dim3(B), 0, stream, g0a, g0b, dinv, N);

    hipLaunchKernelGGL(k_agg96, dim3((N * 24 + B - 1) / B), dim3(B), 0, stream,
                       g0a, off, epk, dinv, b1, h, N);

    hipLaunchKernelGGL(k_gemm2, dim3((N + 127) / 128), dim3(B), 0, stream, h, W2, dinv, g1, N);

    hipLaunchKernelGGL(k_agg40, dim3((N * 10 + B - 1) / B), dim3(B), 0, stream,
                       g1, off, epk, dinv, b2, out, N);

    hipLaunchKernelGGL(k_lsm, dim3((N * 64 + B - 1) / B), dim3(B), 0, stream, out, N);
}

// Round 7
// 218.968 us; speedup vs baseline: 1.0561x; 1.0561x over previous
//
#include <hip/hip_runtime.h>
#include <hip/hip_bf16.h>
#include <hip/hip_fp16.h>
#include <math.h>

#define NN 50000
#define EE 800000
#define FIN 256
#define FH 96
#define FC 40
#define NBK 196   // ceil(50000/256) buckets of 256 nodes

// ---------------- privatized LDS histogram (deg by row, cnt by col) ----------------

__global__ __launch_bounds__(256) void k_hist(const int* __restrict__ ei, int E,
                                              unsigned* __restrict__ copies) {
    __shared__ unsigned hist[12500];
    int b = blockIdx.x;
    int slice = b & 63;
    int half = (b >> 6) & 1;
    int arr = b >> 7;
    const int* ptr = ei + (size_t)arr * E;  // arr=0: row, arr=1: col
    int tid = threadIdx.x;
    for (int i = tid; i < 12500; i += 256) hist[i] = 0u;
    __syncthreads();
    int ES = (E + 63) >> 6;
    int lo = slice * ES, hi = min(lo + ES, E);
    int nlo = half * 25000;
    for (int i = lo + tid; i < hi; i += 256) {
        int rel = ptr[i] - nlo;
        if ((unsigned)rel < 25000u)
            atomicAdd(&hist[rel >> 1], 1u << ((rel & 1) << 4));
    }
    __syncthreads();
    unsigned* dst = copies + (size_t)((arr * 2 + half) * 64 + slice) * 12500;
    for (int i = tid; i < 12500; i += 256) dst[i] = hist[i];
}

// sum the 64 copies -> dinv (float, rsqrt(deg+1)) and cnt (u32)
__global__ void k_reduce(const unsigned* __restrict__ copies,
                         float* __restrict__ dinv, unsigned* __restrict__ cnt) {
    int t = blockIdx.x * blockDim.x + threadIdx.x;  // 0..24999
    if (t >= 25000) return;
    int half = t / 12500, w = t - half * 12500;
    unsigned sr = 0, sc = 0;
    const unsigned* br = copies + (size_t)(half) * 64 * 12500 + w;      // rows
    const unsigned* bc = copies + (size_t)(2 + half) * 64 * 12500 + w;  // cols
#pragma unroll 8
    for (int s = 0; s < 64; ++s) { sr += br[s * 12500]; sc += bc[s * 12500]; }
    int n0 = half * 25000 + 2 * w;
    dinv[n0]     = rsqrtf((float)((sr & 0xffffu) + 1u));
    dinv[n0 + 1] = rsqrtf((float)((sr >> 16) + 1u));
    cnt[n0]     = sc & 0xffffu;
    cnt[n0 + 1] = sc >> 16;
}

// ---------------- exclusive scan of cnt -> off ----------------

__global__ __launch_bounds__(1024) void k_scanA(const unsigned* __restrict__ cnt,
                                                unsigned* __restrict__ off,
                                                unsigned* __restrict__ bsum, int n) {
    __shared__ unsigned s[1024];
    int t = threadIdx.x;
    int i = blockIdx.x * 1024 + t;
    unsigned v = (i < n) ? cnt[i] : 0u;
    s[t] = v;
    __syncthreads();
    for (int o = 1; o < 1024; o <<= 1) {
        unsigned tv = (t >= o) ? s[t - o] : 0u;
        __syncthreads();
        s[t] += tv;
        __syncthreads();
    }
    if (i < n) off[i] = s[t] - v;  // exclusive
    if (t == 1023) bsum[blockIdx.x] = s[1023];
}

__global__ void k_scanB1(unsigned* bsum, int nb) {
    if (threadIdx.x == 0 && blockIdx.x == 0) {
        unsigned run = 0;
        for (int b = 0; b < nb; ++b) { unsigned tv = bsum[b]; bsum[b] = run; run += tv; }
    }
}

__global__ void k_scanB2(unsigned* __restrict__ off, const unsigned* __restrict__ bsum,
                         int n, unsigned e) {
    int i = blockIdx.x * blockDim.x + threadIdx.x;
    if (i < n) off[i] = off[i] + bsum[i >> 10];
    if (i == n) off[n] = e;
}

// gcur[b] = off[b*256]
__global__ void k_initgc(const unsigned* __restrict__ off, unsigned* __restrict__ gcur) {
    int b = threadIdx.x + blockIdx.x * blockDim.x;
    if (b < NBK) gcur[b] = off[b * 256];
}

// ---------------- P1: coarse bucket by col>>8 (count, reserve, place) ----------------

__global__ __launch_bounds__(256) void k_bucket(const int* __restrict__ row,
                                                const int* __restrict__ col,
                                                const float* __restrict__ ew,
                                                unsigned* __restrict__ gcur,
                                                unsigned* __restrict__ bkc,
                                                float2* __restrict__ bkrw, int E) {
    __shared__ unsigned cnt[NBK];
    __shared__ unsigned cur[NBK];
    int tid = threadIdx.x;
    int CH = (E + gridDim.x - 1) / gridDim.x;
    int lo = blockIdx.x * CH, hi = min(lo + CH, E);
    for (int i = tid; i < NBK; i += 256) cnt[i] = 0u;
    __syncthreads();
    for (int i = lo + tid; i < hi; i += 256) atomicAdd(&cnt[col[i] >> 8], 1u);
    __syncthreads();
    for (int i = tid; i < NBK; i += 256) cur[i] = atomicAdd(&gcur[i], cnt[i]);
    __syncthreads();
    for (int i = lo + tid; i < hi; i += 256) {
        int c = col[i];
        unsigned pos = atomicAdd(&cur[c >> 8], 1u);
        bkc[pos] = (unsigned)c;
        float2 p;
        p.x = __int_as_float(row[i]);
        p.y = ew[i];
        bkrw[pos] = p;
    }
}

// ---------------- P2: exact place within bucket ----------------

__global__ __launch_bounds__(256) void k_place(const unsigned* __restrict__ bkc,
                                               const float2* __restrict__ bkrw,
                                               const unsigned* __restrict__ off,
                                               float2* __restrict__ epk, int n) {
    __shared__ unsigned cur[256];
    int b = blockIdx.x;
    int tid = threadIdx.x;
    int node0 = b * 256;
    int node = node0 + tid;
    cur[tid] = off[(node <= n) ? node : n];
    __syncthreads();
    unsigned st = off[node0];
    unsigned en = off[min(node0 + 256, n)];
    for (unsigned i = st + tid; i < en; i += 256) {
        unsigned c = bkc[i];
        unsigned pos = atomicAdd(&cur[c & 255], 1u);
        epk[pos] = bkrw[i];
    }
}

// ---------------- GEMM1: g0h = fp16( dinv ⊙ (x @ W1^T) )  64-row tiles ----------------

__global__ __launch_bounds__(256) void k_gemm1(const float* __restrict__ x,
                                               const float* __restrict__ W,
                                               const float* __restrict__ dinv,
                                               __half* __restrict__ g0h, int n) {
    __shared__ float xs[32][68];   // [k][row]
    __shared__ float ws[32][100];  // [k][col]
    int tid = threadIdx.x;
    int row0 = blockIdx.x * 64;
    int rg = tid & 31, cg = tid >> 5;

    float acc[2][12];
#pragma unroll
    for (int r = 0; r < 2; ++r)
#pragma unroll
        for (int c = 0; c < 12; ++c) acc[r][c] = 0.f;

    for (int k0 = 0; k0 < FIN; k0 += 32) {
        // x tile: 64 rows x 32 k = 512 float4, 2 per thread
#pragma unroll
        for (int i = 0; i < 2; ++i) {
            int f4i = tid + 256 * i;
            int gr = f4i >> 3;         // 0..63
            int kk = (f4i & 7) << 2;
            int grow = row0 + gr;
            float4 v = make_float4(0.f, 0.f, 0.f, 0.f);
            if (grow < n) v = *(const float4*)&x[grow * FIN + k0 + kk];
            xs[kk + 0][gr] = v.x; xs[kk + 1][gr] = v.y;
            xs[kk + 2][gr] = v.z; xs[kk + 3][gr] = v.w;
        }
        // w tile: 96 cols x 32 k = 768 float4, 3 per thread
#pragma unroll
        for (int i = 0; i < 3; ++i) {
            int f4i = tid + 256 * i;
            int wc = f4i >> 3;         // 0..95
            int kk = (f4i & 7) << 2;
            float4 v = *(const float4*)&W[wc * FIN + k0 + kk];
            ws[kk + 0][wc] = v.x; ws[kk + 1][wc] = v.y;
            ws[kk + 2][wc] = v.z; ws[kk + 3][wc] = v.w;
        }
        __syncthreads();
#pragma unroll 8
        for (int k = 0; k < 32; ++k) {
            float2 xv = *(const float2*)&xs[k][2 * rg];
            float4 w0 = *(const float4*)&ws[k][4 * cg];
            float4 w1 = *(const float4*)&ws[k][4 * cg + 32];
            float4 w2 = *(const float4*)&ws[k][4 * cg + 64];
            const float xr[2] = {xv.x, xv.y};
#pragma unroll
            for (int r = 0; r < 2; ++r) {
                acc[r][0]  = fmaf(xr[r], w0.x, acc[r][0]);
                acc[r][1]  = fmaf(xr[r], w0.y, acc[r][1]);
                acc[r][2]  = fmaf(xr[r], w0.z, acc[r][2]);
                acc[r][3]  = fmaf(xr[r], w0.w, acc[r][3]);
                acc[r][4]  = fmaf(xr[r], w1.x, acc[r][4]);
                acc[r][5]  = fmaf(xr[r], w1.y, acc[r][5]);
                acc[r][6]  = fmaf(xr[r], w1.z, acc[r][6]);
                acc[r][7]  = fmaf(xr[r], w1.w, acc[r][7]);
                acc[r][8]  = fmaf(xr[r], w2.x, acc[r][8]);
                acc[r][9]  = fmaf(xr[r], w2.y, acc[r][9]);
                acc[r][10] = fmaf(xr[r], w2.z, acc[r][10]);
                acc[r][11] = fmaf(xr[r], w2.w, acc[r][11]);
            }
        }
        __syncthreads();
    }
#pragma unroll
    for (int r = 0; r < 2; ++r) {
        int grow = row0 + 2 * rg + r;
        if (grow < n) {
            float dv = dinv[grow];
#pragma unroll
            for (int c = 0; c < 3; ++c) {
                __half2 p0 = __floats2half2_rn(dv * acc[r][4 * c + 0], dv * acc[r][4 * c + 1]);
                __half2 p1 = __floats2half2_rn(dv * acc[r][4 * c + 2], dv * acc[r][4 * c + 3]);
                __half2* dst = (__half2*)&g0h[grow * FH + 4 * cg + 32 * c];
                dst[0] = p0; dst[1] = p1;
            }
        }
    }
}

// ---------------- aggregation 96 (fp16 gather): h = relu(dinv[c]*(g0[c]+Σ ew*g0[r])+b1) ----------------

__global__ __launch_bounds__(256) void k_agg96(const __half* __restrict__ g0h,
                                               const unsigned* __restrict__ off,
                                               const float2* __restrict__ epk,
                                               const float* __restrict__ dinv,
                                               const float* __restrict__ b,
                                               float* __restrict__ outh, int n) {
    int tid = blockIdx.x * 256 + threadIdx.x;
    int node = tid / 24;
    int f4 = tid - node * 24;
    if (node >= n) return;
    uint2 raw = *(const uint2*)&g0h[(size_t)node * FH + f4 * 4];
    __half2 ha = *(__half2*)&raw.x, hb = *(__half2*)&raw.y;
    float2 fa = __half22float2(ha), fb = __half22float2(hb);
    float4 acc = make_float4(fa.x, fa.y, fb.x, fb.y);
    unsigned st = off[node], en = off[node + 1];
    for (unsigned e = st; e < en; ++e) {
        float2 p = epk[e];
        int r = __float_as_int(p.x);
        float wv = p.y;
        uint2 g = *(const uint2*)&g0h[(size_t)r * FH + f4 * 4];
        __half2 g0v = *(__half2*)&g.x, g1v = *(__half2*)&g.y;
        float2 v0 = __half22float2(g0v), v1 = __half22float2(g1v);
        acc.x = fmaf(wv, v0.x, acc.x);
        acc.y = fmaf(wv, v0.y, acc.y);
        acc.z = fmaf(wv, v1.x, acc.z);
        acc.w = fmaf(wv, v1.y, acc.w);
    }
    float s = dinv[node];
    float4 bv = ((const float4*)b)[f4];
    acc.x = fmaxf(fmaf(s, acc.x, bv.x), 0.f);
    acc.y = fmaxf(fmaf(s, acc.y, bv.y), 0.f);
    acc.z = fmaxf(fmaf(s, acc.z, bv.z), 0.f);
    acc.w = fmaxf(fmaf(s, acc.w, bv.w), 0.f);
    ((float4*)outh)[node * 24 + f4] = acc;
}

// ---------------- GEMM2: g1h = fp16( dinv ⊙ (h @ W2^T) )  64-row tiles ----------------

__global__ __launch_bounds__(256) void k_gemm2(const float* __restrict__ h,
                                               const float* __restrict__ W,
                                               const float* __restrict__ dinv,
                                               __half* __restrict__ g1h, int n) {
    __shared__ float hs[48][68];   // [k][row]
    __shared__ float w2s[48][44];  // [k][col]
    int tid = threadIdx.x;
    int row0 = blockIdx.x * 64;
    int rg = tid & 31, cg = tid >> 5;

    float acc[2][5];
#pragma unroll
    for (int r = 0; r < 2; ++r)
#pragma unroll
        for (int c = 0; c < 5; ++c) acc[r][c] = 0.f;

    for (int k0 = 0; k0 < FH; k0 += 48) {
        // h tile: 64 rows x 48 k = 768 float4, 3 per thread
#pragma unroll
        for (int i = 0; i < 3; ++i) {
            int f4i = tid + 256 * i;
            int gr = f4i / 12;            // 0..63
            int kk = (f4i - gr * 12) << 2;
            int grow = row0 + gr;
            float4 v = make_float4(0.f, 0.f, 0.f, 0.f);
            if (grow < n) v = *(const float4*)&h[grow * FH + k0 + kk];
            hs[kk + 0][gr] = v.x; hs[kk + 1][gr] = v.y;
            hs[kk + 2][gr] = v.z; hs[kk + 3][gr] = v.w;
        }
        // w tile: 40 cols x 48 k = 480 float4, 2 per thread with guard
#pragma unroll
        for (int i = 0; i < 2; ++i) {
            int f4i = tid + 256 * i;
            if (f4i < 480) {
                int wc = f4i / 12;
                int kk = (f4i - wc * 12) << 2;
                float4 v = *(const float4*)&W[wc * FH + k0 + kk];
                w2s[kk + 0][wc] = v.x; w2s[kk + 1][wc] = v.y;
                w2s[kk + 2][wc] = v.z; w2s[kk + 3][wc] = v.w;
            }
        }
        __syncthreads();
#pragma unroll 8
        for (int k = 0; k < 48; ++k) {
            float2 xv = *(const float2*)&hs[k][2 * rg];
            const float xr[2] = {xv.x, xv.y};
            float wv[5];
#pragma unroll
            for (int c = 0; c < 5; ++c) wv[c] = w2s[k][5 * cg + c];
#pragma unroll
            for (int r = 0; r < 2; ++r)
#pragma unroll
                for (int c = 0; c < 5; ++c)
                    acc[r][c] = fmaf(xr[r], wv[c], acc[r][c]);
        }
        __syncthreads();
    }
#pragma unroll
    for (int r = 0; r < 2; ++r) {
        int grow = row0 + 2 * rg + r;
        if (grow < n) {
            float dv = dinv[grow];
#pragma unroll
            for (int c = 0; c < 5; ++c)
                g1h[(size_t)grow * FC + 5 * cg + c] = __float2half_rn(dv * acc[r][c]);
        }
    }
}

// ---------------- aggregation 40 (fp16 gather): out = dinv[c]*(g1[c]+Σ ew*g1[r])+b2 ----------------

__global__ __launch_bounds__(256) void k_agg40(const __half* __restrict__ g1h,
                                               const unsigned* __restrict__ off,
                                               const float2* __restrict__ epk,
                                               const float* __restrict__ dinv,
                                               const float* __restrict__ b,
                                               float* __restrict__ out, int n) {
    int tid = blockIdx.x * 256 + threadIdx.x;
    int node = tid / 10;
    int f4 = tid - node * 10;
    if (node >= n) return;
    uint2 raw = *(const uint2*)&g1h[(size_t)node * FC + f4 * 4];
    __half2 ha = *(__half2*)&raw.x, hb = *(__half2*)&raw.y;
    float2 fa = __half22float2(ha), fb = __half22float2(hb);
    float4 acc = make_float4(fa.x, fa.y, fb.x, fb.y);
    unsigned st = off[node], en = off[node + 1];
    for (unsigned e = st; e < en; ++e) {
        float2 p = epk[e];
        int r = __float_as_int(p.x);
        float wv = p.y;
        uint2 g = *(const uint2*)&g1h[(size_t)r * FC + f4 * 4];
        __half2 g0v = *(__half2*)&g.x, g1v = *(__half2*)&g.y;
        float2 v0 = __half22float2(g0v), v1 = __half22float2(g1v);
        acc.x = fmaf(wv, v0.x, acc.x);
        acc.y = fmaf(wv, v0.y, acc.y);
        acc.z = fmaf(wv, v1.x, acc.z);
        acc.w = fmaf(wv, v1.y, acc.w);
    }
    float s = dinv[node];
    float4 bv = ((const float4*)b)[f4];
    acc.x = fmaf(s, acc.x, bv.x);
    acc.y = fmaf(s, acc.y, bv.y);
    acc.z = fmaf(s, acc.z, bv.z);
    acc.w = fmaf(s, acc.w, bv.w);
    ((float4*)out)[node * 10 + f4] = acc;
}

// ---------------- log_softmax (wave per row) ----------------

__global__ void k_lsm(float* __restrict__ out, int n) {
    int gtid = blockIdx.x * blockDim.x + threadIdx.x;
    int wid = gtid >> 6;
    int lane = threadIdx.x & 63;
    if (wid >= n) return;
    float vv = 0.f, v = -INFINITY;
    if (lane < FC) {
        vv = out[wid * FC + lane];
        v = vv;
    }
#pragma unroll
    for (int o = 32; o; o >>= 1) v = fmaxf(v, __shfl_xor(v, o));
    float ex = (lane < FC) ? expf(vv - v) : 0.f;
#pragma unroll
    for (int o = 32; o; o >>= 1) ex += __shfl_xor(ex, o);
    float lse = logf(ex) + v;
    if (lane < FC) out[wid * FC + lane] = vv - lse;
}

// ---------------- launch ----------------

extern "C" void kernel_launch(void* const* d_in, const int* in_sizes, int n_in,
                              void* d_out, int out_size, void* d_ws, size_t ws_size,
                              hipStream_t stream) {
    const float* x  = (const float*)d_in[0];
    const int*   ei = (const int*)d_in[1];
    const float* ew = (const float*)d_in[2];
    const float* W1 = (const float*)d_in[3];
    const float* b1 = (const float*)d_in[4];
    const float* W2 = (const float*)d_in[5];
    const float* b2 = (const float*)d_in[6];
    float* out = (float*)d_out;

    const int N = NN;
    const int E = in_sizes[1] / 2;
    const int* row = ei;
    const int* col = ei + E;

    float* ws = (float*)d_ws;
    // workspace layout (4-byte words); total 9,950,976 words = 39.8 MB
    // temporal overlays of region R = [150976, 4950976):
    //   copies [150976,3350976)                      : k_hist -> k_reduce
    //   bkc [150976,950976), bkrw [950976,2550976)   : k_bucket -> k_place
    //   h   [150976,4950976)                         : k_agg96 -> k_gemm2
    // epk [4950976,6550976): k_place -> k_agg40
    // g0h [6550976,8950976): k_gemm1 -> k_agg96 (fp16, N*96)
    // g1h [8950976,9950976): k_gemm2 -> k_agg40 (fp16, N*40)
    float*    dinv   = (float*)(ws + 0);           // N
    unsigned* cnt    = (unsigned*)(ws + 50176);    // N
    unsigned* off    = (unsigned*)(ws + 100352);   // N+1
    unsigned* bsum   = (unsigned*)(ws + 150656);   // 64
    unsigned* gcur   = (unsigned*)(ws + 150720);   // 196 (+pad to 150976)
    unsigned* copies = (unsigned*)(ws + 150976);
    unsigned* bkc    = (unsigned*)(ws + 150976);
    float2*   bkrw   = (float2*)(ws + 950976);
    float*    h      = ws + 150976;
    float2*   epk    = (float2*)(ws + 4950976);
    __half*   g0h    = (__half*)(ws + 6550976);
    __half*   g1h    = (__half*)(ws + 8950976);

    const int B = 256;
    const int NB_SCAN = (N + 1023) / 1024;

    hipLaunchKernelGGL(k_hist, dim3(256), dim3(B), 0, stream, ei, E, copies);
    hipLaunchKernelGGL(k_reduce, dim3((25000 + B - 1) / B), dim3(B), 0, stream, copies, dinv, cnt);

    hipLaunchKernelGGL(k_scanA, dim3(NB_SCAN), dim3(1024), 0, stream, cnt, off, bsum, N);
    hipLaunchKernelGGL(k_scanB1, dim3(1), dim3(64), 0, stream, bsum, NB_SCAN);
    hipLaunchKernelGGL(k_scanB2, dim3((N + 1 + B - 1) / B), dim3(B), 0, stream, off, bsum, N, (unsigned)E);
    hipLaunchKernelGGL(k_initgc, dim3(1), dim3(B), 0, stream, off, gcur);

    hipLaunchKernelGGL(k_bucket, dim3(320), dim3(B), 0, stream, row, col, ew, gcur, bkc, bkrw, E);
    hipLaunchKernelGGL(k_place, dim3(NBK), dim3(B), 0, stream, bkc, bkrw, off, epk, N);

    hipLaunchKernelGGL(k_gemm1, dim3((N + 63) / 64), dim3(B), 0, stream, x, W1, dinv, g0h, N);

    hipLaunchKernelGGL(k_agg96, dim3((N * 24 + B - 1) / B), dim3(B), 0, stream,
                       g0h, off, epk, dinv, b1, h, N);

    hipLaunchKernelGGL(k_gemm2, dim3((N + 63) / 64), dim3(B), 0, stream, h, W2, dinv, g1h, N);

    hipLaunchKernelGGL(k_agg40, dim3((N * 10 + B - 1) / B), dim3(B), 0, stream,
                       g1h, off, epk, dinv, b2, out, N);

    hipLaunchKernelGGL(k_lsm, dim3((N * 64 + B - 1) / B), dim3(B), 0, stream, out, N);
}

// Round 8
// 178.772 us; speedup vs baseline: 1.2936x; 1.2248x over previous
//
#include <hip/hip_runtime.h>
#include <hip/hip_bf16.h>
#include <hip/hip_fp16.h>
#include <math.h>

#define NN 50000
#define EE 800000
#define FIN 256
#define FH 96
#define FC 40
#define NBK 196   // ceil(50000/256) buckets of 256 nodes

typedef _Float16 h4 __attribute__((ext_vector_type(4)));
typedef _Float16 h8 __attribute__((ext_vector_type(8)));
typedef float f32x4 __attribute__((ext_vector_type(4)));

// ---------------- privatized LDS histogram (deg by row, cnt by col) ----------------

__global__ __launch_bounds__(256) void k_hist(const int* __restrict__ ei, int E,
                                              unsigned* __restrict__ copies) {
    __shared__ unsigned hist[12500];
    int b = blockIdx.x;
    int slice = b & 63;
    int half = (b >> 6) & 1;
    int arr = b >> 7;
    const int* ptr = ei + (size_t)arr * E;  // arr=0: row, arr=1: col
    int tid = threadIdx.x;
    for (int i = tid; i < 12500; i += 256) hist[i] = 0u;
    __syncthreads();
    int ES = (E + 63) >> 6;
    int lo = slice * ES, hi = min(lo + ES, E);
    int nlo = half * 25000;
    for (int i = lo + tid; i < hi; i += 256) {
        int rel = ptr[i] - nlo;
        if ((unsigned)rel < 25000u)
            atomicAdd(&hist[rel >> 1], 1u << ((rel & 1) << 4));
    }
    __syncthreads();
    unsigned* dst = copies + (size_t)((arr * 2 + half) * 64 + slice) * 12500;
    for (int i = tid; i < 12500; i += 256) dst[i] = hist[i];
}

// sum the 64 copies -> dinv (float, rsqrt(deg+1)) and cnt (u32)
__global__ void k_reduce(const unsigned* __restrict__ copies,
                         float* __restrict__ dinv, unsigned* __restrict__ cnt) {
    int t = blockIdx.x * blockDim.x + threadIdx.x;  // 0..24999
    if (t >= 25000) return;
    int half = t / 12500, w = t - half * 12500;
    unsigned sr = 0, sc = 0;
    const unsigned* br = copies + (size_t)(half) * 64 * 12500 + w;      // rows
    const unsigned* bc = copies + (size_t)(2 + half) * 64 * 12500 + w;  // cols
#pragma unroll 8
    for (int s = 0; s < 64; ++s) { sr += br[s * 12500]; sc += bc[s * 12500]; }
    int n0 = half * 25000 + 2 * w;
    dinv[n0]     = rsqrtf((float)((sr & 0xffffu) + 1u));
    dinv[n0 + 1] = rsqrtf((float)((sr >> 16) + 1u));
    cnt[n0]     = sc & 0xffffu;
    cnt[n0 + 1] = sc >> 16;
}

// ---------------- exclusive scan of cnt -> off ----------------

__global__ __launch_bounds__(1024) void k_scanA(const unsigned* __restrict__ cnt,
                                                unsigned* __restrict__ off,
                                                unsigned* __restrict__ bsum, int n) {
    __shared__ unsigned s[1024];
    int t = threadIdx.x;
    int i = blockIdx.x * 1024 + t;
    unsigned v = (i < n) ? cnt[i] : 0u;
    s[t] = v;
    __syncthreads();
    for (int o = 1; o < 1024; o <<= 1) {
        unsigned tv = (t >= o) ? s[t - o] : 0u;
        __syncthreads();
        s[t] += tv;
        __syncthreads();
    }
    if (i < n) off[i] = s[t] - v;  // exclusive
    if (t == 1023) bsum[blockIdx.x] = s[1023];
}

__global__ void k_scanB1(unsigned* bsum, int nb) {
    if (threadIdx.x == 0 && blockIdx.x == 0) {
        unsigned run = 0;
        for (int b = 0; b < nb; ++b) { unsigned tv = bsum[b]; bsum[b] = run; run += tv; }
    }
}

__global__ void k_scanB2(unsigned* __restrict__ off, const unsigned* __restrict__ bsum,
                         int n, unsigned e) {
    int i = blockIdx.x * blockDim.x + threadIdx.x;
    if (i < n) off[i] = off[i] + bsum[i >> 10];
    if (i == n) off[n] = e;
}

// gcur[b] = off[b*256]
__global__ void k_initgc(const unsigned* __restrict__ off, unsigned* __restrict__ gcur) {
    int b = threadIdx.x + blockIdx.x * blockDim.x;
    if (b < NBK) gcur[b] = off[b * 256];
}

// ---------------- P1: coarse bucket by col>>8 ----------------

__global__ __launch_bounds__(256) void k_bucket(const int* __restrict__ row,
                                                const int* __restrict__ col,
                                                const float* __restrict__ ew,
                                                unsigned* __restrict__ gcur,
                                                unsigned* __restrict__ bkc,
                                                float2* __restrict__ bkrw, int E) {
    __shared__ unsigned cnt[NBK];
    __shared__ unsigned cur[NBK];
    int tid = threadIdx.x;
    int CH = (E + gridDim.x - 1) / gridDim.x;
    int lo = blockIdx.x * CH, hi = min(lo + CH, E);
    for (int i = tid; i < NBK; i += 256) cnt[i] = 0u;
    __syncthreads();
    for (int i = lo + tid; i < hi; i += 256) atomicAdd(&cnt[col[i] >> 8], 1u);
    __syncthreads();
    for (int i = tid; i < NBK; i += 256) cur[i] = atomicAdd(&gcur[i], cnt[i]);
    __syncthreads();
    for (int i = lo + tid; i < hi; i += 256) {
        int c = col[i];
        unsigned pos = atomicAdd(&cur[c >> 8], 1u);
        bkc[pos] = (unsigned)c;
        float2 p;
        p.x = __int_as_float(row[i]);
        p.y = ew[i];
        bkrw[pos] = p;
    }
}

// ---------------- P2: exact place within bucket ----------------

__global__ __launch_bounds__(256) void k_place(const unsigned* __restrict__ bkc,
                                               const float2* __restrict__ bkrw,
                                               const unsigned* __restrict__ off,
                                               float2* __restrict__ epk, int n) {
    __shared__ unsigned cur[256];
    int b = blockIdx.x;
    int tid = threadIdx.x;
    int node0 = b * 256;
    int node = node0 + tid;
    cur[tid] = off[(node <= n) ? node : n];
    __syncthreads();
    unsigned st = off[node0];
    unsigned en = off[min(node0 + 256, n)];
    for (unsigned i = st + tid; i < en; i += 256) {
        unsigned c = bkc[i];
        unsigned pos = atomicAdd(&cur[c & 255], 1u);
        epk[pos] = bkrw[i];
    }
}

// ---------------- GEMM1 (MFMA fp16): g0h = fp16( dinv ⊙ (x @ W1^T) ) ----------------
// 64x96 tile, 4 waves; wave = 16 rows x 6 col-tiles; K chunked at 64.
// Operand pattern follows m97-verified gemm_bt: both A and B^T fragments are
// contiguous 8-fp16 reads at [row][(l>>4)*8 + ks*32]; C/D: col=l&15, row=(l>>4)*4+reg.

__global__ __launch_bounds__(256) void k_gemm1(const float* __restrict__ x,
                                               const float* __restrict__ W,
                                               const float* __restrict__ dinv,
                                               _Float16* __restrict__ g0h, int n) {
    __shared__ _Float16 xs[64][72];   // pad 64->72: LDS row stride 144B (bank-safe)
    __shared__ _Float16 wsm[96][72];
    int tid = threadIdx.x;
    int row0 = blockIdx.x * 64;
    int l = tid & 63, w = tid >> 6;
    int l15 = l & 15, lg = l >> 4;

    f32x4 acc[6];
#pragma unroll
    for (int c = 0; c < 6; ++c) acc[c] = (f32x4)0.f;

    for (int kc = 0; kc < 4; ++kc) {
        int kbase = kc * 64;
        // stage x: 64 rows x 16 float4 = 1024 items, cvt to fp16
#pragma unroll
        for (int i = 0; i < 4; ++i) {
            int it = tid + 256 * i;
            int r = it >> 4, k4 = it & 15;
            float4 v = make_float4(0.f, 0.f, 0.f, 0.f);
            int gr = row0 + r;
            if (gr < n) v = *(const float4*)&x[gr * FIN + kbase + k4 * 4];
            h4 hv = {(_Float16)v.x, (_Float16)v.y, (_Float16)v.z, (_Float16)v.w};
            *(h4*)&xs[r][k4 * 4] = hv;
        }
        // stage W: 96 rows x 16 float4 = 1536 items
#pragma unroll
        for (int i = 0; i < 6; ++i) {
            int it = tid + 256 * i;
            int r = it >> 4, k4 = it & 15;
            float4 v = *(const float4*)&W[r * FIN + kbase + k4 * 4];
            h4 hv = {(_Float16)v.x, (_Float16)v.y, (_Float16)v.z, (_Float16)v.w};
            *(h4*)&wsm[r][k4 * 4] = hv;
        }
        __syncthreads();
#pragma unroll
        for (int ks = 0; ks < 2; ++ks) {
            h8 a = *(const h8*)&xs[16 * w + l15][ks * 32 + lg * 8];
#pragma unroll
            for (int ct = 0; ct < 6; ++ct) {
                h8 b = *(const h8*)&wsm[ct * 16 + l15][ks * 32 + lg * 8];
                acc[ct] = __builtin_amdgcn_mfma_f32_16x16x32_f16(a, b, acc[ct], 0, 0, 0);
            }
        }
        __syncthreads();
    }
#pragma unroll
    for (int r = 0; r < 4; ++r) {
        int grow = row0 + 16 * w + lg * 4 + r;
        if (grow < n) {
            float dv = dinv[grow];
#pragma unroll
            for (int ct = 0; ct < 6; ++ct)
                g0h[(size_t)grow * FH + ct * 16 + l15] = (_Float16)(dv * acc[ct][r]);
        }
    }
}

// ---------------- aggregation 96 (fp16 gather): h = fp16(relu(dinv[c]*(g0[c]+Σ ew*g0[r])+b1)) ----------------

__global__ __launch_bounds__(256) void k_agg96(const _Float16* __restrict__ g0h,
                                               const unsigned* __restrict__ off,
                                               const float2* __restrict__ epk,
                                               const float* __restrict__ dinv,
                                               const float* __restrict__ b,
                                               _Float16* __restrict__ outh, int n) {
    int tid = blockIdx.x * 256 + threadIdx.x;
    int node = tid / 24;
    int f4 = tid - node * 24;
    if (node >= n) return;
    h4 self = *(const h4*)&g0h[(size_t)node * FH + f4 * 4];
    float4 acc = make_float4((float)self[0], (float)self[1], (float)self[2], (float)self[3]);
    unsigned st = off[node], en = off[node + 1];
    for (unsigned e = st; e < en; ++e) {
        float2 p = epk[e];
        int r = __float_as_int(p.x);
        float wv = p.y;
        h4 g = *(const h4*)&g0h[(size_t)r * FH + f4 * 4];
        acc.x = fmaf(wv, (float)g[0], acc.x);
        acc.y = fmaf(wv, (float)g[1], acc.y);
        acc.z = fmaf(wv, (float)g[2], acc.z);
        acc.w = fmaf(wv, (float)g[3], acc.w);
    }
    float s = dinv[node];
    float4 bv = ((const float4*)b)[f4];
    h4 o;
    o[0] = (_Float16)fmaxf(fmaf(s, acc.x, bv.x), 0.f);
    o[1] = (_Float16)fmaxf(fmaf(s, acc.y, bv.y), 0.f);
    o[2] = (_Float16)fmaxf(fmaf(s, acc.z, bv.z), 0.f);
    o[3] = (_Float16)fmaxf(fmaf(s, acc.w, bv.w), 0.f);
    *(h4*)&outh[(size_t)node * FH + f4 * 4] = o;
}

// ---------------- GEMM2 (MFMA fp16): g1h = fp16( dinv ⊙ (h @ W2^T) ) ----------------
// 64x48 tile (cols 40 padded to 48 with zero rows), K=96 staged whole.

__global__ __launch_bounds__(256) void k_gemm2(const _Float16* __restrict__ h,
                                               const float* __restrict__ W2,
                                               const float* __restrict__ dinv,
                                               _Float16* __restrict__ g1h, int n) {
    __shared__ _Float16 hs[64][104];   // 96+8 pad -> 208B stride
    __shared__ _Float16 wsm[48][104];
    int tid = threadIdx.x;
    int row0 = blockIdx.x * 64;
    int l = tid & 63, w = tid >> 6;
    int l15 = l & 15, lg = l >> 4;

    f32x4 acc[3];
#pragma unroll
    for (int c = 0; c < 3; ++c) acc[c] = (f32x4)0.f;

    // stage h: 64 rows x 24 h4 = 1536 items (fp16 copy)
#pragma unroll
    for (int i = 0; i < 6; ++i) {
        int it = tid + 256 * i;
        int r = it / 24, k4 = it - r * 24;
        int gr = row0 + r;
        h4 hv = {(_Float16)0.f, (_Float16)0.f, (_Float16)0.f, (_Float16)0.f};
        if (gr < n) hv = *(const h4*)&h[(size_t)gr * FH + k4 * 4];
        *(h4*)&hs[r][k4 * 4] = hv;
    }
    // stage W2: 48 rows x 24 h4 = 1152 items (rows 40-47 zero)
#pragma unroll
    for (int i = 0; i < 5; ++i) {
        int it = tid + 256 * i;
        if (it < 1152) {
            int r = it / 24, k4 = it - r * 24;
            h4 hv = {(_Float16)0.f, (_Float16)0.f, (_Float16)0.f, (_Float16)0.f};
            if (r < FC) {
                float4 v = *(const float4*)&W2[r * FH + k4 * 4];
                hv[0] = (_Float16)v.x; hv[1] = (_Float16)v.y;
                hv[2] = (_Float16)v.z; hv[3] = (_Float16)v.w;
            }
            *(h4*)&wsm[r][k4 * 4] = hv;
        }
    }
    __syncthreads();
#pragma unroll
    for (int ks = 0; ks < 3; ++ks) {
        h8 a = *(const h8*)&hs[16 * w + l15][ks * 32 + lg * 8];
#pragma unroll
        for (int ct = 0; ct < 3; ++ct) {
            h8 b = *(const h8*)&wsm[ct * 16 + l15][ks * 32 + lg * 8];
            acc[ct] = __builtin_amdgcn_mfma_f32_16x16x32_f16(a, b, acc[ct], 0, 0, 0);
        }
    }
#pragma unroll
    for (int r = 0; r < 4; ++r) {
        int grow = row0 + 16 * w + lg * 4 + r;
        if (grow < n) {
            float dv = dinv[grow];
#pragma unroll
            for (int ct = 0; ct < 3; ++ct) {
                int colc = ct * 16 + l15;
                if (colc < FC)
                    g1h[(size_t)grow * FC + colc] = (_Float16)(dv * acc[ct][r]);
            }
        }
    }
}

// ---------------- aggregation 40 (fp16 gather): out = dinv[c]*(g1[c]+Σ ew*g1[r])+b2 ----------------

__global__ __launch_bounds__(256) void k_agg40(const _Float16* __restrict__ g1h,
                                               const unsigned* __restrict__ off,
                                               const float2* __restrict__ epk,
                                               const float* __restrict__ dinv,
                                               const float* __restrict__ b,
                                               float* __restrict__ out, int n) {
    int tid = blockIdx.x * 256 + threadIdx.x;
    int node = tid / 10;
    int f4 = tid - node * 10;
    if (node >= n) return;
    h4 self = *(const h4*)&g1h[(size_t)node * FC + f4 * 4];
    float4 acc = make_float4((float)self[0], (float)self[1], (float)self[2], (float)self[3]);
    unsigned st = off[node], en = off[node + 1];
    for (unsigned e = st; e < en; ++e) {
        float2 p = epk[e];
        int r = __float_as_int(p.x);
        float wv = p.y;
        h4 g = *(const h4*)&g1h[(size_t)r * FC + f4 * 4];
        acc.x = fmaf(wv, (float)g[0], acc.x);
        acc.y = fmaf(wv, (float)g[1], acc.y);
        acc.z = fmaf(wv, (float)g[2], acc.z);
        acc.w = fmaf(wv, (float)g[3], acc.w);
    }
    float s = dinv[node];
    float4 bv = ((const float4*)b)[f4];
    acc.x = fmaf(s, acc.x, bv.x);
    acc.y = fmaf(s, acc.y, bv.y);
    acc.z = fmaf(s, acc.z, bv.z);
    acc.w = fmaf(s, acc.w, bv.w);
    ((float4*)out)[node * 10 + f4] = acc;
}

// ---------------- log_softmax (wave per row) ----------------

__global__ void k_lsm(float* __restrict__ out, int n) {
    int gtid = blockIdx.x * blockDim.x + threadIdx.x;
    int wid = gtid >> 6;
    int lane = threadIdx.x & 63;
    if (wid >= n) return;
    float vv = 0.f, v = -INFINITY;
    if (lane < FC) {
        vv = out[wid * FC + lane];
        v = vv;
    }
#pragma unroll
    for (int o = 32; o; o >>= 1) v = fmaxf(v, __shfl_xor(v, o));
    float ex = (lane < FC) ? expf(vv - v) : 0.f;
#pragma unroll
    for (int o = 32; o; o >>= 1) ex += __shfl_xor(ex, o);
    float lse = logf(ex) + v;
    if (lane < FC) out[wid * FC + lane] = vv - lse;
}

// ---------------- launch ----------------

extern "C" void kernel_launch(void* const* d_in, const int* in_sizes, int n_in,
                              void* d_out, int out_size, void* d_ws, size_t ws_size,
                              hipStream_t stream) {
    const float* x  = (const float*)d_in[0];
    const int*   ei = (const int*)d_in[1];
    const float* ew = (const float*)d_in[2];
    const float* W1 = (const float*)d_in[3];
    const float* b1 = (const float*)d_in[4];
    const float* W2 = (const float*)d_in[5];
    const float* b2 = (const float*)d_in[6];
    float* out = (float*)d_out;

    const int N = NN;
    const int E = in_sizes[1] / 2;
    const int* row = ei;
    const int* col = ei + E;

    float* ws = (float*)d_ws;
    // workspace layout (4-byte words); total 9,950,976 words = 39.8 MB
    // temporal overlays of region R = [150976, 4950976):
    //   copies [150976,3350976)                      : k_hist -> k_reduce
    //   bkc [150976,950976), bkrw [950976,2550976)   : k_bucket -> k_place
    //   h   [150976,2550976) (fp16 N*96)             : k_agg96 -> k_gemm2
    // epk [4950976,6550976): k_place -> k_agg40
    // g0h [6550976,8950976): k_gemm1 -> k_agg96 (fp16, N*96)
    // g1h [8950976,9950976): k_gemm2 -> k_agg40 (fp16, N*40)
    float*    dinv   = (float*)(ws + 0);           // N
    unsigned* cnt    = (unsigned*)(ws + 50176);    // N
    unsigned* off    = (unsigned*)(ws + 100352);   // N+1
    unsigned* bsum   = (unsigned*)(ws + 150656);   // 64
    unsigned* gcur   = (unsigned*)(ws + 150720);   // 196 (+pad to 150976)
    unsigned* copies = (unsigned*)(ws + 150976);
    unsigned* bkc    = (unsigned*)(ws + 150976);
    float2*   bkrw   = (float2*)(ws + 950976);
    _Float16* h      = (_Float16*)(ws + 150976);
    float2*   epk    = (float2*)(ws + 4950976);
    _Float16* g0h    = (_Float16*)(ws + 6550976);
    _Float16* g1h    = (_Float16*)(ws + 8950976);

    const int B = 256;
    const int NB_SCAN = (N + 1023) / 1024;

    hipLaunchKernelGGL(k_hist, dim3(256), dim3(B), 0, stream, ei, E, copies);
    hipLaunchKernelGGL(k_reduce, dim3((25000 + B - 1) / B), dim3(B), 0, stream, copies, dinv, cnt);

    hipLaunchKernelGGL(k_scanA, dim3(NB_SCAN), dim3(1024), 0, stream, cnt, off, bsum, N);
    hipLaunchKernelGGL(k_scanB1, dim3(1), dim3(64), 0, stream, bsum, NB_SCAN);
    hipLaunchKernelGGL(k_scanB2, dim3((N + 1 + B - 1) / B), dim3(B), 0, stream, off, bsum, N, (unsigned)E);
    hipLaunchKernelGGL(k_initgc, dim3(1), dim3(B), 0, stream, off, gcur);

    hipLaunchKernelGGL(k_bucket, dim3(320), dim3(B), 0, stream, row, col, ew, gcur, bkc, bkrw, E);
    hipLaunchKernelGGL(k_place, dim3(NBK), dim3(B), 0, stream, bkc, bkrw, off, epk, N);

    hipLaunchKernelGGL(k_gemm1, dim3((N + 63) / 64), dim3(B), 0, stream, x, W1, dinv, g0h, N);

    hipLaunchKernelGGL(k_agg96, dim3((N * 24 + B - 1) / B), dim3(B), 0, stream,
                       g0h, off, epk, dinv, b1, h, N);

    hipLaunchKernelGGL(k_gemm2, dim3((N + 63) / 64), dim3(B), 0, stream, h, W2, dinv, g1h, N);

    hipLaunchKernelGGL(k_agg40, dim3((N * 10 + B - 1) / B), dim3(B), 0, stream,
                       g1h, off, epk, dinv, b2, out, N);

    hipLaunchKernelGGL(k_lsm, dim3((N * 64 + B - 1) / B), dim3(B), 0, stream, out, N);
}

// Round 9
// 158.813 us; speedup vs baseline: 1.4562x; 1.1257x over previous
//
#include <hip/hip_runtime.h>
#include <hip/hip_bf16.h>
#include <hip/hip_fp16.h>
#include <math.h>

#define NN 50000
#define EE 800000
#define FIN 256
#define FH 96
#define FC 40
#define NBK 196   // ceil(50000/256) buckets of 256 nodes

typedef _Float16 h4 __attribute__((ext_vector_type(4)));
typedef _Float16 h8 __attribute__((ext_vector_type(8)));
typedef float f32x4 __attribute__((ext_vector_type(4)));

// ---------------- privatized LDS histogram (deg by row, cnt by col) ----------------

__global__ __launch_bounds__(256) void k_hist(const int* __restrict__ ei, int E,
                                              unsigned* __restrict__ copies) {
    __shared__ unsigned hist[12500];
    int b = blockIdx.x;
    int slice = b & 63;
    int half = (b >> 6) & 1;
    int arr = b >> 7;
    const int* ptr = ei + (size_t)arr * E;  // arr=0: row, arr=1: col
    int tid = threadIdx.x;
    for (int i = tid; i < 12500; i += 256) hist[i] = 0u;
    __syncthreads();
    int ES = (E + 63) >> 6;
    int lo = slice * ES, hi = min(lo + ES, E);
    int nlo = half * 25000;
    for (int i = lo + tid; i < hi; i += 256) {
        int rel = ptr[i] - nlo;
        if ((unsigned)rel < 25000u)
            atomicAdd(&hist[rel >> 1], 1u << ((rel & 1) << 4));
    }
    __syncthreads();
    unsigned* dst = copies + (size_t)((arr * 2 + half) * 64 + slice) * 12500;
    for (int i = tid; i < 12500; i += 256) dst[i] = hist[i];
}

// sum the 64 copies -> dinv (float, rsqrt(deg+1)) and cnt (u32)
__global__ void k_reduce(const unsigned* __restrict__ copies,
                         float* __restrict__ dinv, unsigned* __restrict__ cnt) {
    int t = blockIdx.x * blockDim.x + threadIdx.x;  // 0..24999
    if (t >= 25000) return;
    int half = t / 12500, w = t - half * 12500;
    unsigned sr = 0, sc = 0;
    const unsigned* br = copies + (size_t)(half) * 64 * 12500 + w;      // rows
    const unsigned* bc = copies + (size_t)(2 + half) * 64 * 12500 + w;  // cols
#pragma unroll 8
    for (int s = 0; s < 64; ++s) { sr += br[s * 12500]; sc += bc[s * 12500]; }
    int n0 = half * 25000 + 2 * w;
    dinv[n0]     = rsqrtf((float)((sr & 0xffffu) + 1u));
    dinv[n0 + 1] = rsqrtf((float)((sr >> 16) + 1u));
    cnt[n0]     = sc & 0xffffu;
    cnt[n0 + 1] = sc >> 16;
}

// ---------------- exclusive scan of cnt -> off ----------------

__global__ __launch_bounds__(1024) void k_scanA(const unsigned* __restrict__ cnt,
                                                unsigned* __restrict__ off,
                                                unsigned* __restrict__ bsum, int n) {
    __shared__ unsigned s[1024];
    int t = threadIdx.x;
    int i = blockIdx.x * 1024 + t;
    unsigned v = (i < n) ? cnt[i] : 0u;
    s[t] = v;
    __syncthreads();
    for (int o = 1; o < 1024; o <<= 1) {
        unsigned tv = (t >= o) ? s[t - o] : 0u;
        __syncthreads();
        s[t] += tv;
        __syncthreads();
    }
    if (i < n) off[i] = s[t] - v;  // exclusive
    if (t == 1023) bsum[blockIdx.x] = s[1023];
}

__global__ void k_scanB1(unsigned* bsum, int nb) {
    if (threadIdx.x == 0 && blockIdx.x == 0) {
        unsigned run = 0;
        for (int b = 0; b < nb; ++b) { unsigned tv = bsum[b]; bsum[b] = run; run += tv; }
    }
}

__global__ void k_scanB2(unsigned* __restrict__ off, const unsigned* __restrict__ bsum,
                         int n, unsigned e) {
    int i = blockIdx.x * blockDim.x + threadIdx.x;
    if (i < n) off[i] = off[i] + bsum[i >> 10];
    if (i == n) off[n] = e;
}

// gcur[b] = off[b*256]
__global__ void k_initgc(const unsigned* __restrict__ off, unsigned* __restrict__ gcur) {
    int b = threadIdx.x + blockIdx.x * blockDim.x;
    if (b < NBK) gcur[b] = off[b * 256];
}

// ---------------- P1: coarse bucket by col>>8 ----------------

__global__ __launch_bounds__(256) void k_bucket(const int* __restrict__ row,
                                                const int* __restrict__ col,
                                                const float* __restrict__ ew,
                                                unsigned* __restrict__ gcur,
                                                unsigned* __restrict__ bkc,
                                                float2* __restrict__ bkrw, int E) {
    __shared__ unsigned cnt[NBK];
    __shared__ unsigned cur[NBK];
    int tid = threadIdx.x;
    int CH = (E + gridDim.x - 1) / gridDim.x;
    int lo = blockIdx.x * CH, hi = min(lo + CH, E);
    for (int i = tid; i < NBK; i += 256) cnt[i] = 0u;
    __syncthreads();
    for (int i = lo + tid; i < hi; i += 256) atomicAdd(&cnt[col[i] >> 8], 1u);
    __syncthreads();
    for (int i = tid; i < NBK; i += 256) cur[i] = atomicAdd(&gcur[i], cnt[i]);
    __syncthreads();
    for (int i = lo + tid; i < hi; i += 256) {
        int c = col[i];
        unsigned pos = atomicAdd(&cur[c >> 8], 1u);
        bkc[pos] = (unsigned)c;
        float2 p;
        p.x = __int_as_float(row[i]);
        p.y = ew[i];
        bkrw[pos] = p;
    }
}

// ---------------- P2: exact place within bucket ----------------

__global__ __launch_bounds__(256) void k_place(const unsigned* __restrict__ bkc,
                                               const float2* __restrict__ bkrw,
                                               const unsigned* __restrict__ off,
                                               float2* __restrict__ epk, int n) {
    __shared__ unsigned cur[256];
    int b = blockIdx.x;
    int tid = threadIdx.x;
    int node0 = b * 256;
    int node = node0 + tid;
    cur[tid] = off[(node <= n) ? node : n];
    __syncthreads();
    unsigned st = off[node0];
    unsigned en = off[min(node0 + 256, n)];
    for (unsigned i = st + tid; i < en; i += 256) {
        unsigned c = bkc[i];
        unsigned pos = atomicAdd(&cur[c & 255], 1u);
        epk[pos] = bkrw[i];
    }
}

// ---------------- GEMM1 (MFMA fp16): g0h = fp16( dinv ⊙ (x @ W1^T) ) ----------------

__global__ __launch_bounds__(256) void k_gemm1(const float* __restrict__ x,
                                               const float* __restrict__ W,
                                               const float* __restrict__ dinv,
                                               _Float16* __restrict__ g0h, int n) {
    __shared__ _Float16 xs[64][72];
    __shared__ _Float16 wsm[96][72];
    int tid = threadIdx.x;
    int row0 = blockIdx.x * 64;
    int l = tid & 63, w = tid >> 6;
    int l15 = l & 15, lg = l >> 4;

    f32x4 acc[6];
#pragma unroll
    for (int c = 0; c < 6; ++c) acc[c] = (f32x4)0.f;

    for (int kc = 0; kc < 4; ++kc) {
        int kbase = kc * 64;
#pragma unroll
        for (int i = 0; i < 4; ++i) {
            int it = tid + 256 * i;
            int r = it >> 4, k4 = it & 15;
            float4 v = make_float4(0.f, 0.f, 0.f, 0.f);
            int gr = row0 + r;
            if (gr < n) v = *(const float4*)&x[gr * FIN + kbase + k4 * 4];
            h4 hv = {(_Float16)v.x, (_Float16)v.y, (_Float16)v.z, (_Float16)v.w};
            *(h4*)&xs[r][k4 * 4] = hv;
        }
#pragma unroll
        for (int i = 0; i < 6; ++i) {
            int it = tid + 256 * i;
            int r = it >> 4, k4 = it & 15;
            float4 v = *(const float4*)&W[r * FIN + kbase + k4 * 4];
            h4 hv = {(_Float16)v.x, (_Float16)v.y, (_Float16)v.z, (_Float16)v.w};
            *(h4*)&wsm[r][k4 * 4] = hv;
        }
        __syncthreads();
#pragma unroll
        for (int ks = 0; ks < 2; ++ks) {
            h8 a = *(const h8*)&xs[16 * w + l15][ks * 32 + lg * 8];
#pragma unroll
            for (int ct = 0; ct < 6; ++ct) {
                h8 b = *(const h8*)&wsm[ct * 16 + l15][ks * 32 + lg * 8];
                acc[ct] = __builtin_amdgcn_mfma_f32_16x16x32_f16(a, b, acc[ct], 0, 0, 0);
            }
        }
        __syncthreads();
    }
#pragma unroll
    for (int r = 0; r < 4; ++r) {
        int grow = row0 + 16 * w + lg * 4 + r;
        if (grow < n) {
            float dv = dinv[grow];
#pragma unroll
            for (int ct = 0; ct < 6; ++ct)
                g0h[(size_t)grow * FH + ct * 16 + l15] = (_Float16)(dv * acc[ct][r]);
        }
    }
}

// ---------------- aggregation 96 (fp16 gather, unroll-4 MLP) ----------------

__global__ __launch_bounds__(256) void k_agg96(const _Float16* __restrict__ g0h,
                                               const unsigned* __restrict__ off,
                                               const float2* __restrict__ epk,
                                               const float* __restrict__ dinv,
                                               const float* __restrict__ b,
                                               _Float16* __restrict__ outh, int n) {
    int tid = blockIdx.x * 256 + threadIdx.x;
    int node = tid / 24;
    int f4 = tid - node * 24;
    if (node >= n) return;
    h4 self = *(const h4*)&g0h[(size_t)node * FH + f4 * 4];
    float4 acc = make_float4((float)self[0], (float)self[1], (float)self[2], (float)self[3]);
    unsigned st = off[node], en = off[node + 1];
    unsigned e = st;
    for (; e + 4 <= en; e += 4) {
        float2 p0 = epk[e + 0], p1 = epk[e + 1], p2 = epk[e + 2], p3 = epk[e + 3];
        h4 ga = *(const h4*)&g0h[(size_t)__float_as_int(p0.x) * FH + f4 * 4];
        h4 gb = *(const h4*)&g0h[(size_t)__float_as_int(p1.x) * FH + f4 * 4];
        h4 gc = *(const h4*)&g0h[(size_t)__float_as_int(p2.x) * FH + f4 * 4];
        h4 gd = *(const h4*)&g0h[(size_t)__float_as_int(p3.x) * FH + f4 * 4];
        acc.x = fmaf(p0.y, (float)ga[0], acc.x);
        acc.y = fmaf(p0.y, (float)ga[1], acc.y);
        acc.z = fmaf(p0.y, (float)ga[2], acc.z);
        acc.w = fmaf(p0.y, (float)ga[3], acc.w);
        acc.x = fmaf(p1.y, (float)gb[0], acc.x);
        acc.y = fmaf(p1.y, (float)gb[1], acc.y);
        acc.z = fmaf(p1.y, (float)gb[2], acc.z);
        acc.w = fmaf(p1.y, (float)gb[3], acc.w);
        acc.x = fmaf(p2.y, (float)gc[0], acc.x);
        acc.y = fmaf(p2.y, (float)gc[1], acc.y);
        acc.z = fmaf(p2.y, (float)gc[2], acc.z);
        acc.w = fmaf(p2.y, (float)gc[3], acc.w);
        acc.x = fmaf(p3.y, (float)gd[0], acc.x);
        acc.y = fmaf(p3.y, (float)gd[1], acc.y);
        acc.z = fmaf(p3.y, (float)gd[2], acc.z);
        acc.w = fmaf(p3.y, (float)gd[3], acc.w);
    }
    for (; e < en; ++e) {
        float2 p = epk[e];
        h4 g = *(const h4*)&g0h[(size_t)__float_as_int(p.x) * FH + f4 * 4];
        acc.x = fmaf(p.y, (float)g[0], acc.x);
        acc.y = fmaf(p.y, (float)g[1], acc.y);
        acc.z = fmaf(p.y, (float)g[2], acc.z);
        acc.w = fmaf(p.y, (float)g[3], acc.w);
    }
    float s = dinv[node];
    float4 bv = ((const float4*)b)[f4];
    h4 o;
    o[0] = (_Float16)fmaxf(fmaf(s, acc.x, bv.x), 0.f);
    o[1] = (_Float16)fmaxf(fmaf(s, acc.y, bv.y), 0.f);
    o[2] = (_Float16)fmaxf(fmaf(s, acc.z, bv.z), 0.f);
    o[3] = (_Float16)fmaxf(fmaf(s, acc.w, bv.w), 0.f);
    *(h4*)&outh[(size_t)node * FH + f4 * 4] = o;
}

// ---------------- GEMM2 (MFMA fp16): g1h = fp16( dinv ⊙ (h @ W2^T) ) ----------------

__global__ __launch_bounds__(256) void k_gemm2(const _Float16* __restrict__ h,
                                               const float* __restrict__ W2,
                                               const float* __restrict__ dinv,
                                               _Float16* __restrict__ g1h, int n) {
    __shared__ _Float16 hs[64][104];
    __shared__ _Float16 wsm[48][104];
    int tid = threadIdx.x;
    int row0 = blockIdx.x * 64;
    int l = tid & 63, w = tid >> 6;
    int l15 = l & 15, lg = l >> 4;

    f32x4 acc[3];
#pragma unroll
    for (int c = 0; c < 3; ++c) acc[c] = (f32x4)0.f;

#pragma unroll
    for (int i = 0; i < 6; ++i) {
        int it = tid + 256 * i;
        int r = it / 24, k4 = it - r * 24;
        int gr = row0 + r;
        h4 hv = {(_Float16)0.f, (_Float16)0.f, (_Float16)0.f, (_Float16)0.f};
        if (gr < n) hv = *(const h4*)&h[(size_t)gr * FH + k4 * 4];
        *(h4*)&hs[r][k4 * 4] = hv;
    }
#pragma unroll
    for (int i = 0; i < 5; ++i) {
        int it = tid + 256 * i;
        if (it < 1152) {
            int r = it / 24, k4 = it - r * 24;
            h4 hv = {(_Float16)0.f, (_Float16)0.f, (_Float16)0.f, (_Float16)0.f};
            if (r < FC) {
                float4 v = *(const float4*)&W2[r * FH + k4 * 4];
                hv[0] = (_Float16)v.x; hv[1] = (_Float16)v.y;
                hv[2] = (_Float16)v.z; hv[3] = (_Float16)v.w;
            }
            *(h4*)&wsm[r][k4 * 4] = hv;
        }
    }
    __syncthreads();
#pragma unroll
    for (int ks = 0; ks < 3; ++ks) {
        h8 a = *(const h8*)&hs[16 * w + l15][ks * 32 + lg * 8];
#pragma unroll
        for (int ct = 0; ct < 3; ++ct) {
            h8 b = *(const h8*)&wsm[ct * 16 + l15][ks * 32 + lg * 8];
            acc[ct] = __builtin_amdgcn_mfma_f32_16x16x32_f16(a, b, acc[ct], 0, 0, 0);
        }
    }
#pragma unroll
    for (int r = 0; r < 4; ++r) {
        int grow = row0 + 16 * w + lg * 4 + r;
        if (grow < n) {
            float dv = dinv[grow];
#pragma unroll
            for (int ct = 0; ct < 3; ++ct) {
                int colc = ct * 16 + l15;
                if (colc < FC)
                    g1h[(size_t)grow * FC + colc] = (_Float16)(dv * acc[ct][r]);
            }
        }
    }
}

// ---------------- aggregation 40 (fp16 gather, unroll-4 MLP) ----------------

__global__ __launch_bounds__(256) void k_agg40(const _Float16* __restrict__ g1h,
                                               const unsigned* __restrict__ off,
                                               const float2* __restrict__ epk,
                                               const float* __restrict__ dinv,
                                               const float* __restrict__ b,
                                               float* __restrict__ out, int n) {
    int tid = blockIdx.x * 256 + threadIdx.x;
    int node = tid / 10;
    int f4 = tid - node * 10;
    if (node >= n) return;
    h4 self = *(const h4*)&g1h[(size_t)node * FC + f4 * 4];
    float4 acc = make_float4((float)self[0], (float)self[1], (float)self[2], (float)self[3]);
    unsigned st = off[node], en = off[node + 1];
    unsigned e = st;
    for (; e + 4 <= en; e += 4) {
        float2 p0 = epk[e + 0], p1 = epk[e + 1], p2 = epk[e + 2], p3 = epk[e + 3];
        h4 ga = *(const h4*)&g1h[(size_t)__float_as_int(p0.x) * FC + f4 * 4];
        h4 gb = *(const h4*)&g1h[(size_t)__float_as_int(p1.x) * FC + f4 * 4];
        h4 gc = *(const h4*)&g1h[(size_t)__float_as_int(p2.x) * FC + f4 * 4];
        h4 gd = *(const h4*)&g1h[(size_t)__float_as_int(p3.x) * FC + f4 * 4];
        acc.x = fmaf(p0.y, (float)ga[0], acc.x);
        acc.y = fmaf(p0.y, (float)ga[1], acc.y);
        acc.z = fmaf(p0.y, (float)ga[2], acc.z);
        acc.w = fmaf(p0.y, (float)ga[3], acc.w);
        acc.x = fmaf(p1.y, (float)gb[0], acc.x);
        acc.y = fmaf(p1.y, (float)gb[1], acc.y);
        acc.z = fmaf(p1.y, (float)gb[2], acc.z);
        acc.w = fmaf(p1.y, (float)gb[3], acc.w);
        acc.x = fmaf(p2.y, (float)gc[0], acc.x);
        acc.y = fmaf(p2.y, (float)gc[1], acc.y);
        acc.z = fmaf(p2.y, (float)gc[2], acc.z);
        acc.w = fmaf(p2.y, (float)gc[3], acc.w);
        acc.x = fmaf(p3.y, (float)gd[0], acc.x);
        acc.y = fmaf(p3.y, (float)gd[1], acc.y);
        acc.z = fmaf(p3.y, (float)gd[2], acc.z);
        acc.w = fmaf(p3.y, (float)gd[3], acc.w);
    }
    for (; e < en; ++e) {
        float2 p = epk[e];
        h4 g = *(const h4*)&g1h[(size_t)__float_as_int(p.x) * FC + f4 * 4];
        acc.x = fmaf(p.y, (float)g[0], acc.x);
        acc.y = fmaf(p.y, (float)g[1], acc.y);
        acc.z = fmaf(p.y, (float)g[2], acc.z);
        acc.w = fmaf(p.y, (float)g[3], acc.w);
    }
    float s = dinv[node];
    float4 bv = ((const float4*)b)[f4];
    acc.x = fmaf(s, acc.x, bv.x);
    acc.y = fmaf(s, acc.y, bv.y);
    acc.z = fmaf(s, acc.z, bv.z);
    acc.w = fmaf(s, acc.w, bv.w);
    ((float4*)out)[node * 10 + f4] = acc;
}

// ---------------- log_softmax (wave per row) ----------------

__global__ void k_lsm(float* __restrict__ out, int n) {
    int gtid = blockIdx.x * blockDim.x + threadIdx.x;
    int wid = gtid >> 6;
    int lane = threadIdx.x & 63;
    if (wid >= n) return;
    float vv = 0.f, v = -INFINITY;
    if (lane < FC) {
        vv = out[wid * FC + lane];
        v = vv;
    }
#pragma unroll
    for (int o = 32; o; o >>= 1) v = fmaxf(v, __shfl_xor(v, o));
    float ex = (lane < FC) ? expf(vv - v) : 0.f;
#pragma unroll
    for (int o = 32; o; o >>= 1) ex += __shfl_xor(ex, o);
    float lse = logf(ex) + v;
    if (lane < FC) out[wid * FC + lane] = vv - lse;
}

// ---------------- launch ----------------

extern "C" void kernel_launch(void* const* d_in, const int* in_sizes, int n_in,
                              void* d_out, int out_size, void* d_ws, size_t ws_size,
                              hipStream_t stream) {
    const float* x  = (const float*)d_in[0];
    const int*   ei = (const int*)d_in[1];
    const float* ew = (const float*)d_in[2];
    const float* W1 = (const float*)d_in[3];
    const float* b1 = (const float*)d_in[4];
    const float* W2 = (const float*)d_in[5];
    const float* b2 = (const float*)d_in[6];
    float* out = (float*)d_out;

    const int N = NN;
    const int E = in_sizes[1] / 2;
    const int* row = ei;
    const int* col = ei + E;

    float* ws = (float*)d_ws;
    // workspace layout (4-byte words); total 9,950,976 words = 39.8 MB
    float*    dinv   = (float*)(ws + 0);           // N
    unsigned* cnt    = (unsigned*)(ws + 50176);    // N
    unsigned* off    = (unsigned*)(ws + 100352);   // N+1
    unsigned* bsum   = (unsigned*)(ws + 150656);   // 64
    unsigned* gcur   = (unsigned*)(ws + 150720);   // 196 (+pad to 150976)
    unsigned* copies = (unsigned*)(ws + 150976);
    unsigned* bkc    = (unsigned*)(ws + 150976);
    float2*   bkrw   = (float2*)(ws + 950976);
    _Float16* h      = (_Float16*)(ws + 150976);
    float2*   epk    = (float2*)(ws + 4950976);
    _Float16* g0h    = (_Float16*)(ws + 6550976);
    _Float16* g1h    = (_Float16*)(ws + 8950976);

    const int B = 256;
    const int NB_SCAN = (N + 1023) / 1024;

    hipLaunchKernelGGL(k_hist, dim3(256), dim3(B), 0, stream, ei, E, copies);
    hipLaunchKernelGGL(k_reduce, dim3((25000 + B - 1) / B), dim3(B), 0, stream, copies, dinv, cnt);

    hipLaunchKernelGGL(k_scanA, dim3(NB_SCAN), dim3(1024), 0, stream, cnt, off, bsum, N);
    hipLaunchKernelGGL(k_scanB1, dim3(1), dim3(64), 0, stream, bsum, NB_SCAN);
    hipLaunchKernelGGL(k_scanB2, dim3((N + 1 + B - 1) / B), dim3(B), 0, stream, off, bsum, N, (unsigned)E);
    hipLaunchKernelGGL(k_initgc, dim3(1), dim3(B), 0, stream, off, gcur);

    hipLaunchKernelGGL(k_bucket, dim3(320), dim3(B), 0, stream, row, col, ew, gcur, bkc, bkrw, E);
    hipLaunchKernelGGL(k_place, dim3(NBK), dim3(B), 0, stream, bkc, bkrw, off, epk, N);

    hipLaunchKernelGGL(k_gemm1, dim3((N + 63) / 64), dim3(B), 0, stream, x, W1, dinv, g0h, N);

    hipLaunchKernelGGL(k_agg96, dim3((N * 24 + B - 1) / B), dim3(B), 0, stream,
                       g0h, off, epk, dinv, b1, h, N);

    hipLaunchKernelGGL(k_gemm2, dim3((N + 63) / 64), dim3(B), 0, stream, h, W2, dinv, g1h, N);

    hipLaunchKernelGGL(k_agg40, dim3((N * 10 + B - 1) / B), dim3(B), 0, stream,
                       g1h, off, epk, dinv, b2, out, N);

    hipLaunchKernelGGL(k_lsm, dim3((N * 64 + B - 1) / B), dim3(B), 0, stream, out, N);
}